// Round 1
// baseline (259.133 us; speedup 1.0000x reference)
//
#include <hip/hip_runtime.h>
#include <hip/hip_bf16.h>
#include <cstdint>

namespace {

constexpr int kB = 8;
constexpr int kS = 1024;
constexpr int kD = 768;
constexpr int kH = 12;
constexpr int kDH = 192;        // per-head qkv width (q:64 k:64 v:64)
constexpr int kNQ = kH * kDH;   // 2304
constexpr int kM = kB * kS;     // 8192
constexpr int kDO = 768;

using f32x4 = __attribute__((ext_vector_type(4))) float;
using s16x8 = __attribute__((ext_vector_type(8))) short;
using u16x8 = __attribute__((ext_vector_type(8))) unsigned short;

__device__ __forceinline__ unsigned short f2bf(float f) {
  union { float f; uint32_t u; } v; v.f = f;
  uint32_t u = v.u;
  u += 0x7FFFu + ((u >> 16) & 1u);   // RNE
  return (unsigned short)(u >> 16);
}

__device__ __forceinline__ void load_lds16(const void* g, void* l) {
  __builtin_amdgcn_global_load_lds((__attribute__((address_space(1))) void*)g,
                                   (__attribute__((address_space(3))) void*)l,
                                   16, 0, 0);
}

// ---------------- prep kernels ----------------

__global__ __launch_bounds__(256) void cvt_x_kernel(const float* __restrict__ in,
                                                    unsigned short* __restrict__ out) {
  int i = (blockIdx.x * 256 + threadIdx.x) * 8;
  float4 a = *(const float4*)(in + i);
  float4 b = *(const float4*)(in + i + 4);
  u16x8 o;
  o[0] = f2bf(a.x); o[1] = f2bf(a.y); o[2] = f2bf(a.z); o[3] = f2bf(a.w);
  o[4] = f2bf(b.x); o[5] = f2bf(b.y); o[6] = f2bf(b.z); o[7] = f2bf(b.w);
  *(u16x8*)(out + i) = o;
}

// wt[n][k] = bf16(w[k][n]);  w is [K][N] f32
__global__ __launch_bounds__(256) void cvt_transpose_kernel(const float* __restrict__ w,
                                                            unsigned short* __restrict__ wt,
                                                            int K, int N) {
  __shared__ float tile[32][33];
  int k0 = blockIdx.x * 32, n0 = blockIdx.y * 32;
  int tx = threadIdx.x & 31, ty = threadIdx.x >> 5;  // 32 x 8
  #pragma unroll
  for (int r = 0; r < 32; r += 8)
    tile[ty + r][tx] = w[(size_t)(k0 + ty + r) * N + n0 + tx];
  __syncthreads();
  #pragma unroll
  for (int r = 0; r < 32; r += 8)
    wt[(size_t)(n0 + ty + r) * K + k0 + tx] = f2bf(tile[tx][ty + r]);
}

// ---------------- GEMM (m97 structure, B^T input) ----------------
// MODE 0: bf16 out, scale Q columns (col%192<64) by 0.125
// MODE 1: f32 out + bias
template <int MODE>
__global__ __launch_bounds__(256, 2) void gemm_bt_kernel(
    const unsigned short* __restrict__ A,   // [M][K] bf16
    const unsigned short* __restrict__ Bt,  // [N][K] bf16
    void* __restrict__ Cout,
    const float* __restrict__ bias,
    int M, int N, int K) {
  __shared__ alignas(16) unsigned short Al[128 * 64];
  __shared__ alignas(16) unsigned short Bl[128 * 64];
  const int nT = N >> 7;
  const int tm = blockIdx.x / nT, tn = blockIdx.x % nT;
  const int tid = threadIdx.x;
  const int w = tid >> 6, l = tid & 63;
  const int wr = w >> 1, wc = w & 1;
  const int la = l & 15, g = l >> 4;
  const int sr = l >> 3, sc = l & 7;

  f32x4 acc[4][4] = {};
  const unsigned short* Ag = A + (size_t)(tm * 128) * K;
  const unsigned short* Bg = Bt + (size_t)(tn * 128) * K;

  for (int k0 = 0; k0 < K; k0 += 64) {
    #pragma unroll
    for (int j = 0; j < 4; ++j) {
      int row = w * 32 + j * 8 + sr;
      load_lds16(Ag + (size_t)row * K + k0 + sc * 8, &Al[row * 64 + sc * 8]);
      load_lds16(Bg + (size_t)row * K + k0 + sc * 8, &Bl[row * 64 + sc * 8]);
    }
    __syncthreads();
    #pragma unroll
    for (int kk = 0; kk < 2; ++kk) {
      s16x8 af[4], bfv[4];
      #pragma unroll
      for (int i = 0; i < 4; ++i)
        af[i] = *(const s16x8*)&Al[(wr * 64 + i * 16 + la) * 64 + kk * 32 + g * 8];
      #pragma unroll
      for (int j = 0; j < 4; ++j)
        bfv[j] = *(const s16x8*)&Bl[(wc * 64 + j * 16 + la) * 64 + kk * 32 + g * 8];
      #pragma unroll
      for (int i = 0; i < 4; ++i)
        #pragma unroll
        for (int j = 0; j < 4; ++j)
          acc[i][j] = __builtin_amdgcn_mfma_f32_16x16x32_bf16(af[i], bfv[j], acc[i][j], 0, 0, 0);
    }
    __syncthreads();
  }

  // C/D layout: col = lane&15, row = 4*(lane>>4) + reg   [verified m89/m91]
  #pragma unroll
  for (int i = 0; i < 4; ++i) {
    int row0 = tm * 128 + wr * 64 + i * 16 + g * 4;
    #pragma unroll
    for (int j = 0; j < 4; ++j) {
      int col = tn * 128 + wc * 64 + j * 16 + la;
      if (MODE == 0) {
        unsigned short* C = (unsigned short*)Cout;
        float sc2 = ((col % 192) < 64) ? 0.125f : 1.0f;  // fold 1/sqrt(DQK) into Q
        #pragma unroll
        for (int r = 0; r < 4; ++r)
          C[(size_t)(row0 + r) * N + col] = f2bf(acc[i][j][r] * sc2);
      } else {
        float* C = (float*)Cout;
        float bv = bias[col];
        #pragma unroll
        for (int r = 0; r < 4; ++r)
          C[(size_t)(row0 + r) * N + col] = acc[i][j][r] + bv;
      }
    }
  }
}

// ---------------- fused attention ----------------
// one block per (q-block of 64 rows, head, batch); 4 waves, each owns 16 q-rows
__global__ __launch_bounds__(256, 2) void attn_kernel(
    const unsigned short* __restrict__ qkv,   // [8192][2304] bf16 (Q pre-scaled)
    unsigned short* __restrict__ Ab) {        // [8192][768]  bf16
  const int qb = blockIdx.x, h = blockIdx.y, b = blockIdx.z;
  const int tid = threadIdx.x;
  const int w = tid >> 6, l = tid & 63;
  const int la = l & 15, g = l >> 4;

  __shared__ alignas(16) unsigned short Ql[64 * 64];
  __shared__ alignas(16) unsigned short Kl[64 * 64];
  __shared__ alignas(16) unsigned short Vt[64 * 64];  // transposed: [d][t]
  __shared__ alignas(16) unsigned short Pl[64 * 64];  // wave-private rows

  const size_t base_bs = (size_t)b * kS;
  const size_t qrow0 = base_bs + (size_t)qb * 64;

  // stage Q, XOR-swizzled rows (G4: byte ^= (row&7)<<4)
  {
    int row = tid >> 2, c0 = (tid & 3) * 2;
    const unsigned short* src = qkv + (qrow0 + row) * kNQ + h * kDH + c0 * 8;
    u16x8 v0 = *(const u16x8*)(src);
    u16x8 v1 = *(const u16x8*)(src + 8);
    int x = row & 7;
    *(u16x8*)&Ql[row * 64 + ((c0 ^ x) * 8)] = v0;
    *(u16x8*)&Ql[row * 64 + (((c0 + 1) ^ x) * 8)] = v1;
  }
  // hoist Q fragments (wave w staged exactly its own rows 16w..16w+15)
  s16x8 qf[2];
  {
    int row = w * 16 + la, x = row & 7;
    #pragma unroll
    for (int ks = 0; ks < 2; ++ks)
      qf[ks] = *(const s16x8*)&Ql[row * 64 + (((ks * 4 + g) ^ x) * 8)];
  }

  float mrow[4], lrow[4];
  #pragma unroll
  for (int r = 0; r < 4; ++r) { mrow[r] = -1e30f; lrow[r] = 0.f; }
  f32x4 oacc[4] = {};
  const float LOG2E = 1.44269504088896340736f;

  for (int kt = 0; kt < 16; ++kt) {
    __syncthreads();  // previous iter's LDS reads done before overwrite
    {
      int row = tid >> 2, c0 = (tid & 3) * 2;
      const unsigned short* srcK = qkv + (base_bs + kt * 64 + row) * kNQ + h * kDH + 64 + c0 * 8;
      u16x8 k0v = *(const u16x8*)(srcK);
      u16x8 k1v = *(const u16x8*)(srcK + 8);
      int x = row & 7;
      *(u16x8*)&Kl[row * 64 + ((c0 ^ x) * 8)] = k0v;
      *(u16x8*)&Kl[row * 64 + (((c0 + 1) ^ x) * 8)] = k1v;

      // V transposed into Vt[d][t], swizzle xv(d) = (d&7)^((d>>3)&7)
      int tv = tid >> 2, d0 = (tid & 3) * 16;
      const unsigned short* srcV = qkv + (base_bs + kt * 64 + tv) * kNQ + h * kDH + 128 + d0;
      u16x8 v0 = *(const u16x8*)(srcV);
      u16x8 v1 = *(const u16x8*)(srcV + 8);
      #pragma unroll
      for (int e = 0; e < 8; ++e) {
        int d1 = d0 + e;
        int x1 = (d1 & 7) ^ ((d1 >> 3) & 7);
        Vt[d1 * 64 + (tv ^ (x1 << 3))] = (unsigned short)v0[e];
        int d2 = d0 + 8 + e;
        int x2 = (d2 & 7) ^ ((d2 >> 3) & 7);
        Vt[d2 * 64 + (tv ^ (x2 << 3))] = (unsigned short)v1[e];
      }
    }
    __syncthreads();

    // S-tile = Q K^T (scale folded into Q)
    f32x4 sacc[4] = {};
    #pragma unroll
    for (int ks = 0; ks < 2; ++ks) {
      #pragma unroll
      for (int tb = 0; tb < 4; ++tb) {
        int row = tb * 16 + la, x = row & 7;
        s16x8 kf = *(const s16x8*)&Kl[row * 64 + (((ks * 4 + g) ^ x) * 8)];
        sacc[tb] = __builtin_amdgcn_mfma_f32_16x16x32_bf16(qf[ks], kf, sacc[tb], 0, 0, 0);
      }
    }

    // wave-parallel online softmax; lane's rows are 16w + 4g + r
    #pragma unroll
    for (int r = 0; r < 4; ++r) {
      float m = fmaxf(fmaxf(sacc[0][r], sacc[1][r]), fmaxf(sacc[2][r], sacc[3][r]));
      #pragma unroll
      for (int msk = 1; msk < 16; msk <<= 1) m = fmaxf(m, __shfl_xor(m, msk, 64));
      float mnew = fmaxf(mrow[r], m);
      float corr = exp2f((mrow[r] - mnew) * LOG2E);
      mrow[r] = mnew;
      float s = 0.f;
      #pragma unroll
      for (int tb = 0; tb < 4; ++tb) {
        float p = exp2f((sacc[tb][r] - mnew) * LOG2E);
        sacc[tb][r] = p;
        s += p;
      }
      #pragma unroll
      for (int msk = 1; msk < 16; msk <<= 1) s += __shfl_xor(s, msk, 64);
      lrow[r] = lrow[r] * corr + s;
      #pragma unroll
      for (int db = 0; db < 4; ++db) oacc[db][r] *= corr;
    }

    // P -> LDS (wave-private rows), bf16, swizzled
    #pragma unroll
    for (int r = 0; r < 4; ++r) {
      int prow = w * 16 + g * 4 + r, x = prow & 7;
      #pragma unroll
      for (int tb = 0; tb < 4; ++tb) {
        int col = tb * 16 + la;
        Pl[prow * 64 + (col ^ (x << 3))] = f2bf(sacc[tb][r]);
      }
    }

    // O += P V
    #pragma unroll
    for (int ks = 0; ks < 2; ++ks) {
      int prow = w * 16 + la, x = prow & 7;
      s16x8 pf = *(const s16x8*)&Pl[prow * 64 + (((ks * 4 + g) ^ x) * 8)];
      #pragma unroll
      for (int db = 0; db < 4; ++db) {
        int drow = db * 16 + la;
        int xv = (drow & 7) ^ ((drow >> 3) & 7);
        s16x8 vf = *(const s16x8*)&Vt[drow * 64 + (((ks * 4 + g) ^ xv) * 8)];
        oacc[db] = __builtin_amdgcn_mfma_f32_16x16x32_bf16(pf, vf, oacc[db], 0, 0, 0);
      }
    }
  }

  // epilogue: divide by l, write bf16
  #pragma unroll
  for (int db = 0; db < 4; ++db) {
    #pragma unroll
    for (int r = 0; r < 4; ++r) {
      int row = w * 16 + g * 4 + r;
      Ab[(qrow0 + row) * (size_t)(kH * 64) + h * 64 + db * 16 + la] =
          f2bf(oacc[db][r] / lrow[r]);
    }
  }
}

}  // namespace

extern "C" void kernel_launch(void* const* d_in, const int* in_sizes, int n_in,
                              void* d_out, int out_size, void* d_ws, size_t ws_size,
                              hipStream_t stream) {
  (void)in_sizes; (void)n_in; (void)out_size; (void)ws_size;
  const float* x = (const float*)d_in[0];
  const float* w_qkv = (const float*)d_in[1];
  const float* w_out = (const float*)d_in[2];
  const float* b_out = (const float*)d_in[3];

  unsigned short* Xb = (unsigned short*)d_ws;               // [8192][768]
  unsigned short* WqT = Xb + (size_t)kM * kD;               // [2304][768]
  unsigned short* WoT = WqT + (size_t)kNQ * kD;             // [768][768]
  unsigned short* QKV = WoT + (size_t)kDO * kDO;            // [8192][2304]
  unsigned short* Ab = QKV + (size_t)kM * kNQ;              // [8192][768]

  cvt_x_kernel<<<dim3((kM * kD) / (256 * 8)), dim3(256), 0, stream>>>(x, Xb);
  cvt_transpose_kernel<<<dim3(kD / 32, kNQ / 32), dim3(256), 0, stream>>>(w_qkv, WqT, kD, kNQ);
  cvt_transpose_kernel<<<dim3(kDO / 32, kDO / 32), dim3(256), 0, stream>>>(w_out, WoT, kDO, kDO);

  gemm_bt_kernel<0><<<dim3((kM / 128) * (kNQ / 128)), dim3(256), 0, stream>>>(
      Xb, WqT, (void*)QKV, nullptr, kM, kNQ, kD);

  attn_kernel<<<dim3(kS / 64, kH, kB), dim3(256), 0, stream>>>(QKV, Ab);

  gemm_bt_kernel<1><<<dim3((kM / 128) * (kDO / 128)), dim3(256), 0, stream>>>(
      Ab, WoT, d_out, b_out, kM, kDO, kH * 64);
}

// Round 2
// 252.465 us; speedup vs baseline: 1.0264x; 1.0264x over previous
//
#include <hip/hip_runtime.h>
#include <hip/hip_bf16.h>
#include <cstdint>

namespace {

constexpr int kB = 8;
constexpr int kS = 1024;
constexpr int kD = 768;
constexpr int kH = 12;
constexpr int kDH = 192;        // per-head qkv width in GEMM1 output space (q:64 k:64 v:64)
constexpr int kNQ = kH * kDH;   // 2304 (GEMM1 logical N)
constexpr int kNK = kH * 128;   // 1536 (compacted Q|K buffer stride)
constexpr int kM = kB * kS;     // 8192
constexpr int kDO = 768;

using f32x4 = __attribute__((ext_vector_type(4))) float;
using s16x8 = __attribute__((ext_vector_type(8))) short;
using u16x8 = __attribute__((ext_vector_type(8))) unsigned short;
using u16x4 = __attribute__((ext_vector_type(4))) unsigned short;

__device__ __forceinline__ unsigned short f2bf(float f) {
  union { float f; uint32_t u; } v; v.f = f;
  uint32_t u = v.u;
  u += 0x7FFFu + ((u >> 16) & 1u);   // RNE
  return (unsigned short)(u >> 16);
}

__device__ __forceinline__ void load_lds16(const void* g, void* l) {
  __builtin_amdgcn_global_load_lds((__attribute__((address_space(1))) void*)g,
                                   (__attribute__((address_space(3))) void*)l,
                                   16, 0, 0);
}

// ---------------- prep kernels ----------------

__global__ __launch_bounds__(256) void cvt_x_kernel(const float* __restrict__ in,
                                                    unsigned short* __restrict__ out) {
  int i = (blockIdx.x * 256 + threadIdx.x) * 8;
  float4 a = *(const float4*)(in + i);
  float4 b = *(const float4*)(in + i + 4);
  u16x8 o;
  o[0] = f2bf(a.x); o[1] = f2bf(a.y); o[2] = f2bf(a.z); o[3] = f2bf(a.w);
  o[4] = f2bf(b.x); o[5] = f2bf(b.y); o[6] = f2bf(b.z); o[7] = f2bf(b.w);
  *(u16x8*)(out + i) = o;
}

// wt[n][k] = bf16(w[k][n]);  w is [K][N] f32
__global__ __launch_bounds__(256) void cvt_transpose_kernel(const float* __restrict__ w,
                                                            unsigned short* __restrict__ wt,
                                                            int K, int N) {
  __shared__ float tile[32][33];
  int k0 = blockIdx.x * 32, n0 = blockIdx.y * 32;
  int tx = threadIdx.x & 31, ty = threadIdx.x >> 5;  // 32 x 8
  #pragma unroll
  for (int r = 0; r < 32; r += 8)
    tile[ty + r][tx] = w[(size_t)(k0 + ty + r) * N + n0 + tx];
  __syncthreads();
  #pragma unroll
  for (int r = 0; r < 32; r += 8)
    wt[(size_t)(n0 + ty + r) * K + k0 + tx] = f2bf(tile[tx][ty + r]);
}

// ---------------- GEMM (m97 structure, B^T input) ----------------
// MODE 0: qkv projection epilogue:
//   cols with col%192 <  64 : Q, scaled 0.125, -> QK buf at col h*128+(col%192)
//   cols with col%192 in [64,128): K -> QK buf at col h*128+(col%192)
//   cols with col%192 >= 128: V -> transposed into Vtg[b][h][d][t], packed 8B
// MODE 1: f32 out + bias
template <int MODE>
__global__ __launch_bounds__(256, 2) void gemm_bt_kernel(
    const unsigned short* __restrict__ A,   // [M][K] bf16
    const unsigned short* __restrict__ Bt,  // [N][K] bf16
    void* __restrict__ Cout,
    unsigned short* __restrict__ Vtg,       // MODE 0 only
    const float* __restrict__ bias,         // MODE 1 only
    int M, int N, int K) {
  __shared__ alignas(16) unsigned short Al[128 * 64];
  __shared__ alignas(16) unsigned short Bl[128 * 64];
  const int nT = N >> 7;
  const int tm = blockIdx.x / nT, tn = blockIdx.x % nT;
  const int tid = threadIdx.x;
  const int w = tid >> 6, l = tid & 63;
  const int wr = w >> 1, wc = w & 1;
  const int la = l & 15, g = l >> 4;
  const int sr = l >> 3, sc = l & 7;

  f32x4 acc[4][4] = {};
  const unsigned short* Ag = A + (size_t)(tm * 128) * K;
  const unsigned short* Bg = Bt + (size_t)(tn * 128) * K;

  for (int k0 = 0; k0 < K; k0 += 64) {
    #pragma unroll
    for (int j = 0; j < 4; ++j) {
      int row = w * 32 + j * 8 + sr;
      load_lds16(Ag + (size_t)row * K + k0 + sc * 8, &Al[row * 64 + sc * 8]);
      load_lds16(Bg + (size_t)row * K + k0 + sc * 8, &Bl[row * 64 + sc * 8]);
    }
    __syncthreads();
    #pragma unroll
    for (int kk = 0; kk < 2; ++kk) {
      s16x8 af[4], bfv[4];
      #pragma unroll
      for (int i = 0; i < 4; ++i)
        af[i] = *(const s16x8*)&Al[(wr * 64 + i * 16 + la) * 64 + kk * 32 + g * 8];
      #pragma unroll
      for (int j = 0; j < 4; ++j)
        bfv[j] = *(const s16x8*)&Bl[(wc * 64 + j * 16 + la) * 64 + kk * 32 + g * 8];
      #pragma unroll
      for (int i = 0; i < 4; ++i)
        #pragma unroll
        for (int j = 0; j < 4; ++j)
          acc[i][j] = __builtin_amdgcn_mfma_f32_16x16x32_bf16(af[i], bfv[j], acc[i][j], 0, 0, 0);
    }
    __syncthreads();
  }

  // C/D layout: col = lane&15, row = 4*(lane>>4) + reg   [verified m89/m91]
  #pragma unroll
  for (int i = 0; i < 4; ++i) {
    int row0 = tm * 128 + wr * 64 + i * 16 + g * 4;
    #pragma unroll
    for (int j = 0; j < 4; ++j) {
      int col = tn * 128 + wc * 64 + j * 16 + la;
      if (MODE == 0) {
        int h = col / kDH, colm = col % kDH;   // j-blocks are 16-aligned -> whole block same segment
        if (colm < 128) {
          unsigned short* C = (unsigned short*)Cout;  // QK buf, stride kNK
          float sc2 = (colm < 64) ? 0.125f : 1.0f;    // fold 1/sqrt(DQK) into Q
          int ncol = h * 128 + colm;
          #pragma unroll
          for (int r = 0; r < 4; ++r)
            C[(size_t)(row0 + r) * kNK + ncol] = f2bf(acc[i][j][r] * sc2);
        } else {
          int d = colm - 128;
          int bb = row0 >> 10, t = row0 & 1023;  // row0 multiple of 4 -> same batch for 4 rows
          u16x4 pv;
          #pragma unroll
          for (int r = 0; r < 4; ++r) pv[r] = f2bf(acc[i][j][r]);
          *(u16x4*)&Vtg[((size_t)(bb * kH + h) * 64 + d) * kS + t] = pv;
        }
      } else {
        float* C = (float*)Cout;
        float bv = bias[col];
        #pragma unroll
        for (int r = 0; r < 4; ++r)
          C[(size_t)(row0 + r) * N + col] = acc[i][j][r] + bv;
      }
    }
  }
}

// ---------------- fused attention ----------------
// one block per (q-block of 64 rows, head, batch); 4 waves, each owns 16 q-rows
// LDS 24KB -> 6 blocks/CU, grid = 6 blocks/CU exactly.
__global__ __launch_bounds__(256, 8) void attn_kernel(
    const unsigned short* __restrict__ qk,    // [8192][1536] bf16 (Q pre-scaled | K)
    const unsigned short* __restrict__ Vtg,   // [8][12][64][1024] bf16 (V transposed)
    unsigned short* __restrict__ Ab) {        // [8192][768]  bf16
  const int qb = blockIdx.x, h = blockIdx.y, b = blockIdx.z;
  const int tid = threadIdx.x;
  const int w = tid >> 6, l = tid & 63;
  const int la = l & 15, g = l >> 4;

  __shared__ alignas(16) unsigned short Kl[64 * 64];
  __shared__ alignas(16) unsigned short Vl[64 * 64];  // V^T tile: [d][t]
  __shared__ alignas(16) unsigned short Pl[64 * 64];  // wave-private rows

  const size_t base_bs = (size_t)b * kS;
  const size_t qrow0 = base_bs + (size_t)qb * 64;

  // Q fragments straight from global (wave reads only its own 16 rows)
  s16x8 qf[2];
  {
    const unsigned short* qp = qk + (qrow0 + w * 16 + la) * kNK + h * 128;
    qf[0] = *(const s16x8*)(qp + g * 8);
    qf[1] = *(const s16x8*)(qp + 32 + g * 8);
  }

  // staging geometry: 512 16B-chunks per tile, 2 issues/thread, linear LDS dest,
  // XOR swizzle applied on the GLOBAL source chunk (rule #21 / m173)
  const int c0 = w * 64 + l;        // issue 0: chunks 0..255 (rows 0..31)
  const int c1 = 256 + w * 64 + l;  // issue 1: chunks 256..511 (rows 32..63)
  const int r0 = c0 >> 3, cc0 = (c0 & 7) ^ (r0 & 7);
  const int r1 = c1 >> 3, cc1 = (c1 & 7) ^ (r1 & 7);
  const unsigned short* Kg = qk + (base_bs)*kNK + h * 128 + 64;
  const unsigned short* Vg = Vtg + (size_t)(b * kH + h) * 64 * kS;

  float mrow[4], lrow[4];
  #pragma unroll
  for (int r = 0; r < 4; ++r) { mrow[r] = -1e30f; lrow[r] = 0.f; }
  f32x4 oacc[4] = {};
  const float LOG2E = 1.44269504088896340736f;

  for (int kt = 0; kt < 16; ++kt) {
    __syncthreads();  // previous iter's LDS reads done before overwrite
    load_lds16(Kg + (size_t)(kt * 64 + r0) * kNK + cc0 * 8, &Kl[c0 * 8]);
    load_lds16(Kg + (size_t)(kt * 64 + r1) * kNK + cc1 * 8, &Kl[c1 * 8]);
    load_lds16(Vg + (size_t)r0 * kS + kt * 64 + cc0 * 8, &Vl[c0 * 8]);
    load_lds16(Vg + (size_t)r1 * kS + kt * 64 + cc1 * 8, &Vl[c1 * 8]);
    __syncthreads();

    // S-tile = Q K^T (scale folded into Q)
    f32x4 sacc[4] = {};
    #pragma unroll
    for (int ks = 0; ks < 2; ++ks) {
      #pragma unroll
      for (int tb = 0; tb < 4; ++tb) {
        int row = tb * 16 + la;
        s16x8 kf = *(const s16x8*)&Kl[row * 64 + (((ks * 4 + g) ^ (row & 7)) * 8)];
        sacc[tb] = __builtin_amdgcn_mfma_f32_16x16x32_bf16(qf[ks], kf, sacc[tb], 0, 0, 0);
      }
    }

    // wave-parallel online softmax; lane's rows are 16w + 4g + r
    #pragma unroll
    for (int r = 0; r < 4; ++r) {
      float m = fmaxf(fmaxf(sacc[0][r], sacc[1][r]), fmaxf(sacc[2][r], sacc[3][r]));
      #pragma unroll
      for (int msk = 1; msk < 16; msk <<= 1) m = fmaxf(m, __shfl_xor(m, msk, 64));
      float mnew = fmaxf(mrow[r], m);
      float corr = exp2f((mrow[r] - mnew) * LOG2E);
      mrow[r] = mnew;
      float s = 0.f;
      #pragma unroll
      for (int tb = 0; tb < 4; ++tb) {
        float p = exp2f((sacc[tb][r] - mnew) * LOG2E);
        sacc[tb][r] = p;
        s += p;
      }
      #pragma unroll
      for (int msk = 1; msk < 16; msk <<= 1) s += __shfl_xor(s, msk, 64);
      lrow[r] = lrow[r] * corr + s;
      #pragma unroll
      for (int db = 0; db < 4; ++db) oacc[db][r] *= corr;
    }

    // P -> LDS (wave-private rows), bf16, swizzled
    #pragma unroll
    for (int r = 0; r < 4; ++r) {
      int prow = w * 16 + g * 4 + r, x = prow & 7;
      #pragma unroll
      for (int tb = 0; tb < 4; ++tb) {
        int col = tb * 16 + la;
        Pl[prow * 64 + (col ^ (x << 3))] = f2bf(sacc[tb][r]);
      }
    }

    // O += P V
    #pragma unroll
    for (int ks = 0; ks < 2; ++ks) {
      int prow = w * 16 + la;
      s16x8 pf = *(const s16x8*)&Pl[prow * 64 + (((ks * 4 + g) ^ (prow & 7)) * 8)];
      #pragma unroll
      for (int db = 0; db < 4; ++db) {
        int drow = db * 16 + la;
        s16x8 vf = *(const s16x8*)&Vl[drow * 64 + (((ks * 4 + g) ^ (drow & 7)) * 8)];
        oacc[db] = __builtin_amdgcn_mfma_f32_16x16x32_bf16(pf, vf, oacc[db], 0, 0, 0);
      }
    }
  }

  // epilogue: divide by l, write bf16
  #pragma unroll
  for (int db = 0; db < 4; ++db) {
    #pragma unroll
    for (int r = 0; r < 4; ++r) {
      int row = w * 16 + g * 4 + r;
      Ab[(qrow0 + row) * (size_t)(kH * 64) + h * 64 + db * 16 + la] =
          f2bf(oacc[db][r] / lrow[r]);
    }
  }
}

}  // namespace

extern "C" void kernel_launch(void* const* d_in, const int* in_sizes, int n_in,
                              void* d_out, int out_size, void* d_ws, size_t ws_size,
                              hipStream_t stream) {
  (void)in_sizes; (void)n_in; (void)out_size; (void)ws_size;
  const float* x = (const float*)d_in[0];
  const float* w_qkv = (const float*)d_in[1];
  const float* w_out = (const float*)d_in[2];
  const float* b_out = (const float*)d_in[3];

  unsigned short* Xb = (unsigned short*)d_ws;               // [8192][768]   12.6MB
  unsigned short* WqT = Xb + (size_t)kM * kD;               // [2304][768]    3.5MB
  unsigned short* WoT = WqT + (size_t)kNQ * kD;             // [768][768]     1.2MB
  unsigned short* QK = WoT + (size_t)kDO * kDO;             // [8192][1536]  25.2MB
  unsigned short* Vtg = QK + (size_t)kM * kNK;              // [96][64][1024] 12.6MB
  unsigned short* Ab = Vtg + (size_t)kB * kH * 64 * kS;     // [8192][768]   12.6MB

  cvt_x_kernel<<<dim3((kM * kD) / (256 * 8)), dim3(256), 0, stream>>>(x, Xb);
  cvt_transpose_kernel<<<dim3(kD / 32, kNQ / 32), dim3(256), 0, stream>>>(w_qkv, WqT, kD, kNQ);
  cvt_transpose_kernel<<<dim3(kDO / 32, kDO / 32), dim3(256), 0, stream>>>(w_out, WoT, kDO, kDO);

  gemm_bt_kernel<0><<<dim3((kM / 128) * (kNQ / 128)), dim3(256), 0, stream>>>(
      Xb, WqT, (void*)QK, Vtg, nullptr, kM, kNQ, kD);

  attn_kernel<<<dim3(kS / 64, kH, kB), dim3(256), 0, stream>>>(QK, Vtg, Ab);

  gemm_bt_kernel<1><<<dim3((kM / 128) * (kDO / 128)), dim3(256), 0, stream>>>(
      Ab, WoT, d_out, nullptr, b_out, kM, kDO, kH * 64);
}

// Round 4
// 210.965 us; speedup vs baseline: 1.2283x; 1.1967x over previous
//
#include <hip/hip_runtime.h>
#include <hip/hip_bf16.h>
#include <cstdint>

namespace {

constexpr int kB = 8;
constexpr int kS = 1024;
constexpr int kD = 768;
constexpr int kH = 12;
constexpr int kDH = 192;        // per-head qkv width in GEMM1 output space (q:64 k:64 v:64)
constexpr int kNQ = kH * kDH;   // 2304 (GEMM1 logical N)
constexpr int kNK = kH * 128;   // 1536 (compacted Q|K buffer stride)
constexpr int kM = kB * kS;     // 8192
constexpr int kDO = 768;

using f32x4 = __attribute__((ext_vector_type(4))) float;
using f32x16 = __attribute__((ext_vector_type(16))) float;
using s16x8 = __attribute__((ext_vector_type(8))) short;
using u16x8 = __attribute__((ext_vector_type(8))) unsigned short;
using u16x4 = __attribute__((ext_vector_type(4))) unsigned short;

__device__ __forceinline__ unsigned short f2bf(float f) {
  union { float f; uint32_t u; } v; v.f = f;
  uint32_t u = v.u;
  u += 0x7FFFu + ((u >> 16) & 1u);   // RNE
  return (unsigned short)(u >> 16);
}

__device__ __forceinline__ unsigned packbf(float a, float b) {
  return (unsigned)f2bf(a) | ((unsigned)f2bf(b) << 16);
}

__device__ __forceinline__ void load_lds16(const void* g, void* l) {
  __builtin_amdgcn_global_load_lds((__attribute__((address_space(1))) void*)g,
                                   (__attribute__((address_space(3))) void*)l,
                                   16, 0, 0);
}

// Build PV B-frag (8 bf16, one 16-k group) from own 8 P-values using verified
// primitives only (f2bf + shfl_xor). Own values (t-offsets per S^T C-layout):
//   hi=0 lanes: t {0,1, 2,3, 8,9, 10,11};  hi=1 lanes: t {4..7, 12..15}
// Needed: word e-pair j covers t = hi*8 + 2j, hi*8 + 2j+1.
__device__ __forceinline__ s16x8 repack8(int hi, float p0, float p1, float p2, float p3,
                                         float p4, float p5, float p6, float p7) {
  unsigned x0 = packbf(p0, p1);
  unsigned x1 = packbf(p2, p3);
  unsigned x2 = packbf(p4, p5);
  unsigned x3 = packbf(p6, p7);
  unsigned y0 = (unsigned)__shfl_xor((int)x0, 32, 64);
  unsigned y1 = (unsigned)__shfl_xor((int)x1, 32, 64);
  unsigned y2 = (unsigned)__shfl_xor((int)x2, 32, 64);
  unsigned y3 = (unsigned)__shfl_xor((int)x3, 32, 64);
  union { unsigned u[4]; s16x8 v; } r;
  r.u[0] = hi ? y2 : x0;   // t(0,1) | t(8,9)
  r.u[1] = hi ? y3 : x1;   // t(2,3) | t(10,11)
  r.u[2] = hi ? x2 : y0;   // t(4,5) | t(12,13)
  r.u[3] = hi ? x3 : y1;   // t(6,7) | t(14,15)
  return r.v;
}

// ---------------- prep kernels ----------------

__global__ __launch_bounds__(256) void cvt_x_kernel(const float* __restrict__ in,
                                                    unsigned short* __restrict__ out) {
  int i = (blockIdx.x * 256 + threadIdx.x) * 8;
  float4 a = *(const float4*)(in + i);
  float4 b = *(const float4*)(in + i + 4);
  u16x8 o;
  o[0] = f2bf(a.x); o[1] = f2bf(a.y); o[2] = f2bf(a.z); o[3] = f2bf(a.w);
  o[4] = f2bf(b.x); o[5] = f2bf(b.y); o[6] = f2bf(b.z); o[7] = f2bf(b.w);
  *(u16x8*)(out + i) = o;
}

// wt[n][k] = bf16(w[k][n]);  w is [K][N] f32
__global__ __launch_bounds__(256) void cvt_transpose_kernel(const float* __restrict__ w,
                                                            unsigned short* __restrict__ wt,
                                                            int K, int N) {
  __shared__ float tile[32][33];
  int k0 = blockIdx.x * 32, n0 = blockIdx.y * 32;
  int tx = threadIdx.x & 31, ty = threadIdx.x >> 5;  // 32 x 8
  #pragma unroll
  for (int r = 0; r < 32; r += 8)
    tile[ty + r][tx] = w[(size_t)(k0 + ty + r) * N + n0 + tx];
  __syncthreads();
  #pragma unroll
  for (int r = 0; r < 32; r += 8)
    wt[(size_t)(n0 + ty + r) * K + k0 + tx] = f2bf(tile[tx][ty + r]);
}

// ---------------- GEMM (m97 structure, B^T input) — exact round-2 (verified) ----------------
// MODE 0: qkv projection epilogue:
//   col%192 <  64 : Q scaled 0.125 -> QK buf col h*128+(col%192)
//   col%192 in [64,128): K -> QK buf
//   col%192 >= 128: V -> transposed into Vtg[b][h][d][t], packed 8B
// MODE 1: f32 out + bias
template <int MODE>
__global__ __launch_bounds__(256, 2) void gemm_bt_kernel(
    const unsigned short* __restrict__ A,   // [M][K] bf16
    const unsigned short* __restrict__ Bt,  // [N][K] bf16
    void* __restrict__ Cout,
    unsigned short* __restrict__ Vtg,       // MODE 0 only
    const float* __restrict__ bias,         // MODE 1 only
    int M, int N, int K) {
  __shared__ alignas(16) unsigned short Al[128 * 64];
  __shared__ alignas(16) unsigned short Bl[128 * 64];
  const int nT = N >> 7;
  const int tm = blockIdx.x / nT, tn = blockIdx.x % nT;
  const int tid = threadIdx.x;
  const int w = tid >> 6, l = tid & 63;
  const int wr = w >> 1, wc = w & 1;
  const int la = l & 15, g = l >> 4;
  const int sr = l >> 3, sc = l & 7;

  f32x4 acc[4][4] = {};
  const unsigned short* Ag = A + (size_t)(tm * 128) * K;
  const unsigned short* Bg = Bt + (size_t)(tn * 128) * K;

  for (int k0 = 0; k0 < K; k0 += 64) {
    #pragma unroll
    for (int j = 0; j < 4; ++j) {
      int row = w * 32 + j * 8 + sr;
      load_lds16(Ag + (size_t)row * K + k0 + sc * 8, &Al[row * 64 + sc * 8]);
      load_lds16(Bg + (size_t)row * K + k0 + sc * 8, &Bl[row * 64 + sc * 8]);
    }
    __syncthreads();
    #pragma unroll
    for (int kk = 0; kk < 2; ++kk) {
      s16x8 af[4], bfv[4];
      #pragma unroll
      for (int i = 0; i < 4; ++i)
        af[i] = *(const s16x8*)&Al[(wr * 64 + i * 16 + la) * 64 + kk * 32 + g * 8];
      #pragma unroll
      for (int j = 0; j < 4; ++j)
        bfv[j] = *(const s16x8*)&Bl[(wc * 64 + j * 16 + la) * 64 + kk * 32 + g * 8];
      #pragma unroll
      for (int i = 0; i < 4; ++i)
        #pragma unroll
        for (int j = 0; j < 4; ++j)
          acc[i][j] = __builtin_amdgcn_mfma_f32_16x16x32_bf16(af[i], bfv[j], acc[i][j], 0, 0, 0);
    }
    __syncthreads();
  }

  // C/D layout: col = lane&15, row = 4*(lane>>4) + reg   [verified m89/m91]
  #pragma unroll
  for (int i = 0; i < 4; ++i) {
    int row0 = tm * 128 + wr * 64 + i * 16 + g * 4;
    #pragma unroll
    for (int j = 0; j < 4; ++j) {
      int col = tn * 128 + wc * 64 + j * 16 + la;
      if (MODE == 0) {
        int h = col / kDH, colm = col % kDH;
        if (colm < 128) {
          unsigned short* C = (unsigned short*)Cout;  // QK buf, stride kNK
          float sc2 = (colm < 64) ? 0.125f : 1.0f;    // fold 1/sqrt(DQK) into Q
          int ncol = h * 128 + colm;
          #pragma unroll
          for (int r = 0; r < 4; ++r)
            C[(size_t)(row0 + r) * kNK + ncol] = f2bf(acc[i][j][r]

 * sc2);
        } else {
          int d = colm - 128;
          int bb = row0 >> 10, t = row0 & 1023;
          u16x4 pv;
          #pragma unroll
          for (int r = 0; r < 4; ++r) pv[r] = f2bf(acc[i][j][r]);
          *(u16x4*)&Vtg[((size_t)(bb * kH + h) * 64 + d) * kS + t] = pv;
        }
      } else {
        float* C = (float*)Cout;
        float bv = bias[col];
        #pragma unroll
        for (int r = 0; r < 4; ++r)
          C[(size_t)(row0 + r) * N + col] = acc[i][j][r] + bv;
      }
    }
  }
}

// ---------------- fused attention (32x32 swapped-QK^T, safe primitives) ----------------
// 4 waves x 32 q-rows (QBLK=128), KVBLK=64. S^T = mfma(K,Q): lane owns one q-row,
// 32 t-values in regs. In-register softmax (tree + shfl_xor(32)), f2bf+shfl repack,
// O^T = mfma(Vt,P).
__global__ __launch_bounds__(256, 3) void attn_kernel(
    const unsigned short* __restrict__ qk,    // [8192][1536] bf16 (Q pre-scaled | K)
    const unsigned short* __restrict__ Vtg,   // [8][12][64][1024] bf16 (V transposed)
    unsigned short* __restrict__ Ab) {        // [8192][768]  bf16
  const int id = blockIdx.x;
  const int b = id & 7;
  const int h = (id >> 3) % kH;
  const int qb = id / (kH * 8);
  const int tid = threadIdx.x;
  const int w = tid >> 6, l = tid & 63;
  const int q0 = l & 31, hi = l >> 5;

  __shared__ alignas(16) unsigned short Kl[64 * 64];
  __shared__ alignas(16) unsigned short Vl[64 * 64];  // V^T tile: [d][t]

  const size_t base_bs = (size_t)b * kS;
  const size_t qrow0 = base_bs + (size_t)qb * 128;
  const size_t myq = qrow0 + w * 32 + q0;

  // Q fragments (B-operand): lane holds Q[q0][kg*16 + hi*8 + e]
  s16x8 qf[4];
  {
    const unsigned short* qp = qk + myq * kNK + h * 128 + hi * 8;
    #pragma unroll
    for (int kg = 0; kg < 4; ++kg) qf[kg] = *(const s16x8*)(qp + kg * 16);
  }

  // staging: 512 16B-chunks per tile, 2 issues/thread, linear LDS dest,
  // XOR swizzle on the GLOBAL source chunk (rule #21 / m173)
  const int c0 = w * 64 + l;
  const int c1 = 256 + w * 64 + l;
  const int r0 = c0 >> 3, cc0 = (c0 & 7) ^ (r0 & 7);
  const int r1 = c1 >> 3, cc1 = (c1 & 7) ^ (r1 & 7);
  const unsigned short* Kg = qk + base_bs * kNK + h * 128 + 64;
  const unsigned short* Vg = Vtg + (size_t)(b * kH + h) * 64 * kS;

  const float LOG2E = 1.44269504088896340736f;
  float m2 = -1e30f;   // running max, log2 domain
  float lrow = 0.f;
  f32x16 oacc[2] = {};

  for (int kt = 0; kt < 16; ++kt) {
    __syncthreads();
    load_lds16(Kg + (size_t)(kt * 64 + r0) * kNK + cc0 * 8, &Kl[c0 * 8]);
    load_lds16(Kg + (size_t)(kt * 64 + r1) * kNK + cc1 * 8, &Kl[c1 * 8]);
    load_lds16(Vg + (size_t)r0 * kS + kt * 64 + cc0 * 8, &Vl[c0 * 8]);
    load_lds16(Vg + (size_t)r1 * kS + kt * 64 + cc1 * 8, &Vl[c1 * 8]);
    __syncthreads();

    // S^T tiles: sacc[tb] covers t in [tb*32, tb*32+32), q = q0
    f32x16 sacc[2] = {};
    #pragma unroll
    for (int tb = 0; tb < 2; ++tb) {
      const int tl = tb * 32 + q0, xr = tl & 7;
      #pragma unroll
      for (int kg = 0; kg < 4; ++kg) {
        s16x8 kf = *(const s16x8*)&Kl[tl * 64 + (((kg * 2 + hi) ^ xr) * 8)];
        sacc[tb] = __builtin_amdgcn_mfma_f32_32x32x16_bf16(kf, qf[kg], sacc[tb], 0, 0, 0);
      }
    }

    // row max: in-register tree over own 32 values + one cross-half shfl
    float mx[16];
    #pragma unroll
    for (int r = 0; r < 16; ++r) mx[r] = fmaxf(sacc[0][r], sacc[1][r]);
    #pragma unroll
    for (int s2 = 8; s2 >= 1; s2 >>= 1)
      #pragma unroll
      for (int r = 0; r < s2; ++r) mx[r] = fmaxf(mx[r], mx[r + s2]);
    float pmax = fmaxf(mx[0], __shfl_xor(mx[0], 32, 64));
    float rx2 = pmax * LOG2E;
    // defer-max (T13): THR=8 natural = 11.54 in log2 domain
    if (!__all(rx2 - m2 <= 11.5416f)) {
      float m2n = fmaxf(m2, rx2);
      float corr = exp2f(m2 - m2n);
      m2 = m2n;
      lrow *= corr;
      #pragma unroll
      for (int db = 0; db < 2; ++db)
        #pragma unroll
        for (int r = 0; r < 16; ++r) oacc[db][r] *= corr;
    }

    float p[32];
    #pragma unroll
    for (int tb = 0; tb < 2; ++tb)
      #pragma unroll
      for (int r = 0; r < 16; ++r)
        p[tb * 16 + r] = exp2f(fmaf(sacc[tb][r], LOG2E, -m2));

    float sm[16];
    #pragma unroll
    for (int r = 0; r < 16; ++r) sm[r] = p[r] + p[16 + r];
    #pragma unroll
    for (int s2 = 8; s2 >= 1; s2 >>= 1)
      #pragma unroll
      for (int r = 0; r < s2; ++r) sm[r] += sm[r + s2];
    lrow += sm[0] + __shfl_xor(sm[0], 32, 64);

    // P -> B-frags, one per 16-t k-group
    s16x8 pb0 = repack8(hi, p[0], p[1], p[2], p[3], p[4], p[5], p[6], p[7]);
    s16x8 pb1 = repack8(hi, p[8], p[9], p[10], p[11], p[12], p[13], p[14], p[15]);
    s16x8 pb2 = repack8(hi, p[16], p[17], p[18], p[19], p[20], p[21], p[22], p[23]);
    s16x8 pb3 = repack8(hi, p[24], p[25], p[26], p[27], p[28], p[29], p[30], p[31]);

    // O^T += V^T P  (A = V^T rows d, B = P cols q)
    #pragma unroll
    for (int db = 0; db < 2; ++db) {
      const int dl = db * 32 + q0, xr = dl & 7;
      s16x8 v0 = *(const s16x8*)&Vl[dl * 64 + (((0 + hi) ^ xr) * 8)];
      s16x8 v1 = *(const s16x8*)&Vl[dl * 64 + (((2 + hi) ^ xr) * 8)];
      s16x8 v2 = *(const s16x8*)&Vl[dl * 64 + (((4 + hi) ^ xr) * 8)];
      s16x8 v3 = *(const s16x8*)&Vl[dl * 64 + (((6 + hi) ^ xr) * 8)];
      oacc[db] = __builtin_amdgcn_mfma_f32_32x32x16_bf16(v0, pb0, oacc[db], 0, 0, 0);
      oacc[db] = __builtin_amdgcn_mfma_f32_32x32x16_bf16(v1, pb1, oacc[db], 0, 0, 0);
      oacc[db] = __builtin_amdgcn_mfma_f32_32x32x16_bf16(v2, pb2, oacc[db], 0, 0, 0);
      oacc[db] = __builtin_amdgcn_mfma_f32_32x32x16_bf16(v3, pb3, oacc[db], 0, 0, 0);
    }
  }

  // epilogue: O^T reg r -> d = db*32 + 8*(r>>2) + 4*hi + (r&3); q = q0 (lane-local)
  float inv = 1.0f / lrow;
  unsigned short* dst = Ab + myq * (size_t)(kH * 64) + h * 64;
  #pragma unroll
  for (int db = 0; db < 2; ++db)
    #pragma unroll
    for (int rq = 0; rq < 4; ++rq) {
      u16x4 pv;
      #pragma unroll
      for (int j = 0; j < 4; ++j) pv[j] = f2bf(oacc[db][rq * 4 + j] * inv);
      *(u16x4*)&dst[db * 32 + rq * 8 + hi * 4] = pv;
    }
}

}  // namespace

extern "C" void kernel_launch(void* const* d_in, const int* in_sizes, int n_in,
                              void* d_out, int out_size, void* d_ws, size_t ws_size,
                              hipStream_t stream) {
  (void)in_sizes; (void)n_in; (void)out_size; (void)ws_size;
  const float* x = (const float*)d_in[0];
  const float* w_qkv = (const float*)d_in[1];
  const float* w_out = (const float*)d_in[2];
  const float* b_out = (const float*)d_in[3];

  unsigned short* Xb = (unsigned short*)d_ws;               // [8192][768]   12.6MB
  unsigned short* WqT = Xb + (size_t)kM * kD;               // [2304][768]    3.5MB
  unsigned short* WoT = WqT + (size_t)kNQ * kD;             // [768][768]     1.2MB
  unsigned short* QK = WoT + (size_t)kDO * kDO;             // [8192][1536]  25.2MB
  unsigned short* Vtg = QK + (size_t)kM * kNK;              // [96][64][1024] 12.6MB
  unsigned short* Ab = Vtg + (size_t)kB * kH * 64 * kS;     // [8192][768]   12.6MB

  cvt_x_kernel<<<dim3((kM * kD) / (256 * 8)), dim3(256), 0, stream>>>(x, Xb);
  cvt_transpose_kernel<<<dim3(kD / 32, kNQ / 32), dim3(256), 0, stream>>>(w_qkv, WqT, kD, kNQ);
  cvt_transpose_kernel<<<dim3(kDO / 32, kDO / 32), dim3(256), 0, stream>>>(w_out, WoT, kDO, kDO);

  gemm_bt_kernel<0><<<dim3((kM / 128) * (kNQ / 128)), dim3(256), 0, stream>>>(
      Xb, WqT, (void*)QK, Vtg, nullptr, kM, kNQ, kD);

  attn_kernel<<<dim3((kS / 128) * kH * kB), dim3(256), 0, stream>>>(QK, Vtg, Ab);

  gemm_bt_kernel<1><<<dim3((kM / 128) * (kDO / 128)), dim3(256), 0, stream>>>(
      Ab, WoT, d_out, nullptr, b_out, kM, kDO, kH * 64);
}